// Round 11
// baseline (272.685 us; speedup 1.0000x reference)
//
#include <hip/hip_runtime.h>

// ---------------------------------------------------------------------------
// Fused GQA attention: B=2, L=2048, D=1024, H=16, G=2, HPG=8, DQK=DV=128.
// Inputs fp32, OUTPUT fp32. bf16 MFMA compute, fp32 accumulation.
// 16x16x32 layouts (measured m89/m91): A[m=lane&15][k=(lane>>4)*8+j],
//   B[k][n=lane&15], C/D row=(lane>>4)*4+reg, col=lane&15.
// 32x32x16 layouts (verified on-HW R10, absmax 0.031): A[m=lane&31][k],
//   B[k=(lane>>5)*8+j][n=lane&31], C/D col=lane&31,
//   row=(reg&3)+8*(reg>>2)+4*(lane>>5).
// Attention: R11 geometry = 2 waves/block (2 heads sharing K/V) x 32 qrows,
// TWO complementary passes (qt = 63-p, then p) -> every block runs exactly
// 33-34 K-iters and all 512 blocks (2/CU, 72 KB LDS) stay resident the whole
// kernel. This removes R10's long-block straggler (makespan was pinned at 32
// iters x ~2900cyc serial chain with ~1 live block/CU, occupancy 12%).
// Softmax: unshifted exp2 domain (shift-invariant; scores are O(1)).
// ---------------------------------------------------------------------------

typedef __bf16 bf16;
typedef __bf16 bf16x8 __attribute__((ext_vector_type(8)));
typedef __bf16 bf16x4 __attribute__((ext_vector_type(4)));
typedef float f32x4 __attribute__((ext_vector_type(4)));
typedef float f32x16 __attribute__((ext_vector_type(16)));
typedef float float4v __attribute__((ext_vector_type(4)));

#define MFMA_BF16(a, b, c) __builtin_amdgcn_mfma_f32_16x16x32_bf16((a), (b), (c), 0, 0, 0)
#define MFMA32(a, b, c)    __builtin_amdgcn_mfma_f32_32x32x16_bf16((a), (b), (c), 0, 0, 0)

static constexpr int Bz = 2, Lz = 2048, Dz = 1024;
static constexpr int Hz = 16, Gz = 2;
static constexpr int DQKz = 128, DVz = 128;

__device__ __forceinline__ void async_copy16(const bf16* g, bf16* l) {
    __builtin_amdgcn_global_load_lds(
        (const __attribute__((address_space(1))) unsigned int*)g,
        (__attribute__((address_space(3))) unsigned int*)l, 16, 0, 0);
}

// ---------------- prep: cvt q/k/v + all 4 weight transposes, one launch -----
__global__ __launch_bounds__(256) void prep(
    const float* __restrict__ q, const float* __restrict__ k,
    const float* __restrict__ v, bf16* __restrict__ dq,
    bf16* __restrict__ dk, bf16* __restrict__ dv,
    const float* __restrict__ Wq, const float* __restrict__ Wk,
    const float* __restrict__ Wv, const float* __restrict__ Wo,
    bf16* __restrict__ WqT, bf16* __restrict__ WkT,
    bf16* __restrict__ WvT, bf16* __restrict__ WoT)
{
    int bid = blockIdx.x;
    if (bid < 6144) {
        const float* s = bid < 2048 ? q : (bid < 4096 ? k : v);
        bf16* d = bid < 2048 ? dq : (bid < 4096 ? dk : dv);
        int i = (bid & 2047) * 2048 + threadIdx.x * 8;
        float4v a = *(const float4v*)(s + i);
        float4v b = *(const float4v*)(s + i + 4);
        bf16x8 o;
        #pragma unroll
        for (int j = 0; j < 4; ++j) { o[j] = (bf16)a[j]; o[j + 4] = (bf16)b[j]; }
        *(bf16x8*)(d + i) = o;
        return;
    }
    bid -= 6144;
    const float* W; bf16* WT; int K, N;
    if (bid < 2048)      { W = Wq; WT = WqT; K = 1024; N = 2048; }
    else if (bid < 2304) { W = Wk; WT = WkT; K = 1024; N = 256;  bid -= 2048; }
    else if (bid < 2560) { W = Wv; WT = WvT; K = 1024; N = 256;  bid -= 2304; }
    else                 { W = Wo; WT = WoT; K = 2048; N = 1024; bid -= 2560; }
    int tiles_n = N >> 5;
    int n0 = (bid % tiles_n) * 32, k0 = (bid / tiles_n) * 32;

    __shared__ bf16 t[32][33];
    int tx = threadIdx.x & 31, ty = threadIdx.x >> 5;
    #pragma unroll
    for (int i = 0; i < 4; ++i)
        t[ty + i * 8][tx] = (bf16)W[(size_t)(k0 + ty + i * 8) * N + n0 + tx];
    __syncthreads();
    #pragma unroll
    for (int i = 0; i < 4; ++i)
        WT[(size_t)(n0 + ty + i * 8) * K + k0 + tx] = t[tx][ty + i * 8];
}

// ---------------- 4-wave GEMM body: 128x128 tile, 4x4 acc/wave, dbuf --------
template <typename TC>
__device__ __forceinline__ void gemm_tile4(
    const bf16* __restrict__ A, const bf16* __restrict__ BT,
    const float* __restrict__ bias, float scale, TC* __restrict__ C,
    int M, int N, int K, int m0, int n0, bool trans_out,
    bf16 (&As)[2][128 * 64], bf16 (&Bs)[2][128 * 64])
{
    const int tid  = threadIdx.x;        // 256
    const int wave = tid >> 6;
    const int lane = tid & 63;
    const int quad = lane >> 4;
    const int l16  = lane & 15;
    const int sw   = l16 & 7;
    const int wm = wave >> 1, wn = wave & 1;

    f32x4 acc[4][4] = {};

    auto stage = [&](int k0, int buf) {
        #pragma unroll
        for (int s = 0; s < 4; ++s) {
            int i = s * 256 + tid;
            int row = i >> 3, c = (i & 7) ^ (row & 7);
            async_copy16(A + (size_t)(m0 + row) * K + k0 + c * 8, &As[buf][i * 8]);
        }
        #pragma unroll
        for (int s = 0; s < 4; ++s) {
            int i = s * 256 + tid;
            int row = i >> 3, c = (i & 7) ^ (row & 7);
            async_copy16(BT + (size_t)(n0 + row) * K + k0 + c * 8, &Bs[buf][i * 8]);
        }
    };

    stage(0, 0);
    int cur = 0;
    for (int k0 = 0; k0 < K; k0 += 64) {
        __syncthreads();
        if (k0 + 64 < K) stage(k0 + 64, cur ^ 1);

        #pragma unroll
        for (int ks = 0; ks < 2; ++ks) {
            bf16x8 af[4], bfv[4];
            #pragma unroll
            for (int mt = 0; mt < 4; ++mt)
                af[mt] = *(const bf16x8*)(&As[cur][((wm * 64 + mt * 16 + l16) * 8
                                                    + ((ks * 4 + quad) ^ sw)) * 8]);
            #pragma unroll
            for (int nt = 0; nt < 4; ++nt)
                bfv[nt] = *(const bf16x8*)(&Bs[cur][((wn * 64 + nt * 16 + l16) * 8
                                                     + ((ks * 4 + quad) ^ sw)) * 8]);
            #pragma unroll
            for (int mt = 0; mt < 4; ++mt)
                #pragma unroll
                for (int nt = 0; nt < 4; ++nt)
                    acc[mt][nt] = MFMA_BF16(af[mt], bfv[nt], acc[mt][nt]);
        }
        cur ^= 1;
    }

    #pragma unroll
    for (int nt = 0; nt < 4; ++nt) {
        int col = n0 + wn * 64 + nt * 16 + l16;
        float bv = bias[col];
        #pragma unroll
        for (int mt = 0; mt < 4; ++mt) {
            int row = m0 + wm * 64 + mt * 16 + quad * 4;
            if (trans_out) {
                struct V4 { TC v[4]; } o;
                #pragma unroll
                for (int r = 0; r < 4; ++r)
                    o.v[r] = (TC)((acc[mt][nt][r] + bv) * scale);
                *(V4*)(&C[(size_t)col * M + row]) = o;
            } else {
                #pragma unroll
                for (int r = 0; r < 4; ++r)
                    C[(size_t)(row + r) * N + col] =
                        (TC)((acc[mt][nt][r] + bv) * scale);
            }
        }
    }
}

// ---------------- Q+K+V projections: 640 x 256-thr, XCD-swizzled ------------
__global__ __launch_bounds__(256, 2) void proj_qkv(
    const bf16* __restrict__ aq, const bf16* __restrict__ ak,
    const bf16* __restrict__ av, const bf16* __restrict__ WqT,
    const bf16* __restrict__ WkT, const bf16* __restrict__ WvT,
    const float* __restrict__ bq, const float* __restrict__ bk,
    const float* __restrict__ bv, const float* __restrict__ qsc,
    bf16* __restrict__ Qw, bf16* __restrict__ Kw, bf16* __restrict__ VwT)
{
    __shared__ bf16 As[2][128 * 64];
    __shared__ bf16 Bs[2][128 * 64];
    int bid = blockIdx.x;
    if (bid < 512) {
        int xcd = bid & 7, rest = bid >> 3;       // same-m blocks share bid%8
        int n = rest & 15, mg = rest >> 4;
        int m = mg * 8 + xcd;
        float scale = qsc[0] * 0.08838834764831845f * 1.4426950408889634f;
        gemm_tile4<bf16>(aq, WqT, bq, scale, Qw, 4096, 2048, 1024,
                         m * 128, n * 128, false, As, Bs);
    } else if (bid < 576) {
        int b2 = bid - 512;
        gemm_tile4<bf16>(ak, WkT, bk, 1.0f, Kw, 4096, 256, 1024,
                         (b2 >> 1) * 128, (b2 & 1) * 128, false, As, Bs);
    } else {
        int b2 = bid - 576;
        gemm_tile4<bf16>(av, WvT, bv, 1.0f, VwT, 4096, 256, 1024,
                         (b2 >> 1) * 128, (b2 & 1) * 128, true, As, Bs);
    }
}

// ---------------- output projection: 128x64 tiles, 512 blocks, 3/CU ---------
__global__ __launch_bounds__(256, 3) void proj_o(
    const bf16* __restrict__ Cw, const bf16* __restrict__ WoT,
    const float* __restrict__ bo, float* __restrict__ out)
{
    __shared__ bf16 As[2][128 * 64];   // 32 KB
    __shared__ bf16 Bs[2][64 * 64];    // 16 KB -> 48 KB total, 3 blocks/CU

    const int tid  = threadIdx.x;      // 256
    const int wave = tid >> 6;
    const int lane = tid & 63;
    const int quad = lane >> 4;
    const int l16  = lane & 15;
    const int sw   = l16 & 7;
    const int wm = wave >> 1, wn = wave & 1;

    int xcd = blockIdx.x & 7, rest = blockIdx.x >> 3;   // rest 0..63
    int n = rest & 15, mg = rest >> 4;                  // n 0..15, mg 0..3
    int m = mg * 8 + xcd;                               // m 0..31
    const int m0 = m * 128, n0 = n * 64;
    const int M = 4096, N = 1024, K = 2048;

    f32x4 acc[4][2] = {};

    auto stage = [&](int k0, int buf) {
        #pragma unroll
        for (int s = 0; s < 4; ++s) {
            int i = s * 256 + tid;
            int row = i >> 3, c = (i & 7) ^ (row & 7);
            async_copy16(Cw + (size_t)(m0 + row) * K + k0 + c * 8, &As[buf][i * 8]);
        }
        #pragma unroll
        for (int s = 0; s < 2; ++s) {
            int i = s * 256 + tid;
            int row = i >> 3, c = (i & 7) ^ (row & 7);
            async_copy16(WoT + (size_t)(n0 + row) * K + k0 + c * 8, &Bs[buf][i * 8]);
        }
    };

    stage(0, 0);
    int cur = 0;
    for (int k0 = 0; k0 < K; k0 += 64) {
        __syncthreads();
        if (k0 + 64 < K) stage(k0 + 64, cur ^ 1);

        #pragma unroll
        for (int ks = 0; ks < 2; ++ks) {
            bf16x8 af[4], bfv[2];
            #pragma unroll
            for (int mt = 0; mt < 4; ++mt)
                af[mt] = *(const bf16x8*)(&As[cur][((wm * 64 + mt * 16 + l16) * 8
                                                    + ((ks * 4 + quad) ^ sw)) * 8]);
            #pragma unroll
            for (int nt = 0; nt < 2; ++nt)
                bfv[nt] = *(const bf16x8*)(&Bs[cur][((wn * 32 + nt * 16 + l16) * 8
                                                     + ((ks * 4 + quad) ^ sw)) * 8]);
            #pragma unroll
            for (int mt = 0; mt < 4; ++mt)
                #pragma unroll
                for (int nt = 0; nt < 2; ++nt)
                    acc[mt][nt] = MFMA_BF16(af[mt], bfv[nt], acc[mt][nt]);
        }
        cur ^= 1;
    }

    #pragma unroll
    for (int nt = 0; nt < 2; ++nt) {
        int col = n0 + wn * 32 + nt * 16 + l16;
        float bv = bo[col];
        #pragma unroll
        for (int mt = 0; mt < 4; ++mt) {
            int row = m0 + wm * 64 + mt * 16 + quad * 4;
            #pragma unroll
            for (int r = 0; r < 4; ++r)
                out[(size_t)(row + r) * N + col] = acc[mt][nt][r] + bv;
        }
    }
}

// ---------------- flash attention: 32x32 MFMA, 2 heads/block, two-pass ------
// grid 512 x 128 thr (2 waves). Decode: b = bid&1, g = (bid>>1)&1,
// hpin = (bid>>2)&3, p = bid>>4 (0..31); h = g*8 + hpin*2 + wave.
// Pass 0: qt = 63-p; pass 1: qt = p (32-row tiles) -> uniform 33-34 K-iters
// per block; all 512 blocks co-resident (72 KB LDS -> 2/CU) start to finish.
__global__ __launch_bounds__(128, 2) void attn_fused(
    const bf16* __restrict__ Q,    // [B*L, H*128], pre-scaled by qsc/sqrt(d)*log2e
    const bf16* __restrict__ Kp,   // [B*L, G*128]
    const bf16* __restrict__ VT,   // [G*128, B*L]
    bf16* __restrict__ ctx)        // [B*L, H*128]
{
    __shared__ bf16 Kb[2][64 * 128];   // 32 KB  [key][dqk], 16 chunks/row swz
    __shared__ bf16 Vb[2][128 * 64];   // 32 KB  [dv][key], 8 chunks/row swz
    __shared__ bf16 Ps[2][32 * 64];    // 8 KB   per-wave [qrow][key], swz

    const int tid  = threadIdx.x;      // 0..127
    const int wave = tid >> 6;         // 0..1
    const int lane = tid & 63;
    const int l32  = lane & 31;
    const int half = lane >> 5;
    const int sw8  = lane & 7;

    const int bid  = blockIdx.x;
    const int b    = bid & 1;
    const int g    = (bid >> 1) & 1;
    const int hpin = (bid >> 2) & 3;
    const int p    = bid >> 4;         // 0..31
    const int h    = g * 8 + hpin * 2 + wave;

    const bf16* kgbase = Kp + (size_t)(b * Lz) * (Gz * DQKz) + g * DQKz;
    const bf16* vgbase = VT + (size_t)(g * DVz) * (Bz * Lz) + b * Lz;

    auto stage = [&](int kt, int buf) {
        const bf16* kb = kgbase + (size_t)(kt * 64) * (Gz * DQKz);
        #pragma unroll
        for (int s = 0; s < 8; ++s) {
            int i = s * 128 + tid;
            int key = i >> 4, c = (i & 15) ^ (key & 7);
            async_copy16(kb + (size_t)key * (Gz * DQKz) + c * 8, &Kb[buf][i * 8]);
        }
        const bf16* vb = vgbase + kt * 64;
        #pragma unroll
        for (int s = 0; s < 8; ++s) {
            int i = s * 128 + tid;
            int dv = i >> 3, c = (i & 7) ^ (dv & 7);
            async_copy16(vb + (size_t)dv * (Bz * Lz) + c * 8, &Vb[buf][i * 8]);
        }
    };

    bf16* ps = Ps[wave];

    for (int pass = 0; pass < 2; ++pass) {
        const int qt   = pass == 0 ? (63 - p) : p;
        const int q0   = qt * 32;
        const int nkt  = (qt >> 1) + 1;
        const int qrow = q0 + l32;

        // Q B-frags: B[k=(lane>>5)*8+j][n=qrow=lane&31]
        bf16x8 qf[8];
        {
            const bf16* qbase = Q + (size_t)(b * Lz + qrow) * (Hz * DQKz) + h * DQKz;
            #pragma unroll
            for (int kc = 0; kc < 8; ++kc)
                qf[kc] = *(const bf16x8*)(qbase + kc * 16 + half * 8);
        }

        f32x16 oacc[4] = {};       // O^T[dv][q]: dv = dvg*32 + rowmap, q = l32
        float lsum = 0.0f;

        if (pass) __syncthreads();  // other wave may still read pass-0 buffers
        stage(0, 0);
        int cur = 0;

        for (int kt = 0; kt < nkt; ++kt) {
            __syncthreads();            // drains async loads issued last iter
            if (kt + 1 < nkt) stage(kt + 1, cur ^ 1);

            const bf16* kcur = Kb[cur];
            const bf16* vcur = Vb[cur];

            // S^T = K Q^T : 2 key-groups x 8 k-chunks
            f32x16 sacc[2] = {};
            #pragma unroll
            for (int kg = 0; kg < 2; ++kg) {
                const int row = kg * 32 + l32;
                #pragma unroll
                for (int kc = 0; kc < 8; ++kc) {
                    bf16x8 kf = *(const bf16x8*)(&kcur[row * 128
                                                       + (((kc * 2 + half) ^ sw8) * 8)]);
                    sacc[kg] = MFMA32(kf, qf[kc], sacc[kg]);
                }
            }

            // P = exp2(S), mask diagonal tile, accumulate row sum, write P^T
            const int kv0 = kt * 64;
            const bool diag = (kt == nkt - 1);
            #pragma unroll
            for (int kg = 0; kg < 2; ++kg) {
                float pv[16];
                if (diag) {
                    #pragma unroll
                    for (int r = 0; r < 16; ++r) {
                        int key = kv0 + kg * 32 + (r & 3) + 8 * (r >> 2) + 4 * half;
                        pv[r] = (key > qrow) ? 0.0f : exp2f(sacc[kg][r]);
                    }
                } else {
                    #pragma unroll
                    for (int r = 0; r < 16; ++r)
                        pv[r] = exp2f(sacc[kg][r]);
                }
                #pragma unroll
                for (int r = 0; r < 16; ++r) lsum += pv[r];
                #pragma unroll
                for (int i = 0; i < 4; ++i) {
                    bf16x4 pk;
                    #pragma unroll
                    for (int r = 0; r < 4; ++r) pk[r] = (bf16)pv[i * 4 + r];
                    int chunk = i + kg * 4;
                    *(bf16x4*)(&ps[l32 * 64 + ((chunk ^ sw8) << 3) + half * 4]) = pk;
                }
            }

            // O^T += V^T P^T : 4 key-chunks x 4 dv-groups
            #pragma unroll
            for (int kc = 0; kc < 4; ++kc) {
                bf16x8 pf = *(const bf16x8*)(&ps[l32 * 64
                                                 + (((kc * 2 + half) ^ sw8) << 3)]);
                #pragma unroll
                for (int dvg = 0; dvg < 4; ++dvg) {
                    const int row = dvg * 32 + l32;
                    bf16x8 vf = *(const bf16x8*)(&vcur[row * 64
                                                       + (((kc * 2 + half) ^ sw8) * 8)]);
                    oacc[dvg] = MFMA32(vf, pf, oacc[dvg]);
                }
            }
            cur ^= 1;
        }

        // row sum: other half-wave holds the other 32 keys of each row
        lsum += __shfl_xor(lsum, 32);
        const float inv = 1.0f / lsum;

        // epilogue: dv = dvg*32 + 8*i + 4*half + (r&3), q = qrow
        bf16* cb = ctx + (size_t)(b * Lz + qrow) * (Hz * DVz) + h * DVz;
        #pragma unroll
        for (int dvg = 0; dvg < 4; ++dvg) {
            #pragma unroll
            for (int i = 0; i < 4; ++i) {
                bf16x4 o4;
                #pragma unroll
                for (int r = 0; r < 4; ++r)
                    o4[r] = (bf16)(oacc[dvg][i * 4 + r] * inv);
                *(bf16x4*)(&cb[dvg * 32 + 8 * i + 4 * half]) = o4;
            }
        }
    }
}

// ---------------------------------------------------------------------------
extern "C" void kernel_launch(void* const* d_in, const int* in_sizes, int n_in,
                              void* d_out, int out_size, void* d_ws, size_t ws_size,
                              hipStream_t stream)
{
    (void)in_sizes; (void)n_in; (void)out_size; (void)ws_size;

    const float* in_q = (const float*)d_in[0];
    const float* in_k = (const float*)d_in[1];
    const float* in_v = (const float*)d_in[2];
    const float* Wq   = (const float*)d_in[3];
    const float* bq   = (const float*)d_in[4];
    const float* Wk   = (const float*)d_in[5];
    const float* bk   = (const float*)d_in[6];
    const float* Wv   = (const float*)d_in[7];
    const float* bv   = (const float*)d_in[8];
    const float* Wo   = (const float*)d_in[9];
    const float* bo   = (const float*)d_in[10];
    const float* qsc  = (const float*)d_in[11];
    float* out = (float*)d_out;

    const int M = Bz * Lz;                       // 4096

    // workspace (bf16 elems), ~53 MB; ak/av alias Cw (consumed before attn
    // writes ctx there).
    bf16* aq  = (bf16*)d_ws;                     // 4M
    bf16* WqT = aq  + (size_t)M * Dz;            // 2M
    bf16* WkT = WqT + (size_t)2048 * 1024;       // 0.25M
    bf16* WvT = WkT + (size_t)256 * 1024;        // 0.25M
    bf16* WoT = WvT + (size_t)256 * 1024;        // 2M
    bf16* Qw  = WoT + (size_t)1024 * 2048;       // 8M
    bf16* Kw  = Qw  + (size_t)M * 2048;          // 1M
    bf16* VwT = Kw  + (size_t)M * 256;           // 1M
    bf16* Cw  = VwT + (size_t)256 * M;           // 8M
    bf16* ak  = Cw;                              // alias (4M)
    bf16* av  = Cw + (size_t)M * Dz;             // alias (4M)

    // 1) prep: cvt + weight transposes
    prep<<<dim3(10752), dim3(256), 0, stream>>>(
        in_q, in_k, in_v, aq, ak, av, Wq, Wk, Wv, Wo, WqT, WkT, WvT, WoT);

    // 2) Q/K/V projections (640 x 256-thr, 4x4 acc, XCD-swizzled)
    proj_qkv<<<dim3(640), dim3(256), 0, stream>>>(
        aq, ak, av, WqT, WkT, WvT, bq, bk, bv, qsc, Qw, Kw, VwT);

    // 3) attention: 2-wave two-pass blocks, uniform 33-34 iters, 2 blocks/CU
    attn_fused<<<dim3(512), dim3(128), 0, stream>>>(Qw, Kw, VwT, Cw);

    // 4) output projection -> fp32 out (128x64 tiles, 3 blocks/CU)
    proj_o<<<dim3(512), dim3(256), 0, stream>>>(Cw, WoT, bo, out);
}

// Round 12
// 260.039 us; speedup vs baseline: 1.0486x; 1.0486x over previous
//
#include <hip/hip_runtime.h>

// ---------------------------------------------------------------------------
// Fused GQA attention: B=2, L=2048, D=1024, H=16, G=2, HPG=8, DQK=DV=128.
// Inputs fp32, OUTPUT fp32. bf16 MFMA compute, fp32 accumulation.
// 16x16x32 layouts (measured m89/m91): A[m=lane&15][k=(lane>>4)*8+j],
//   B[k][n=lane&15], C/D row=(lane>>4)*4+reg, col=lane&15.
// 32x32x16 layouts (verified on-HW R10): A[m=lane&31][k=(lane>>5)*8+j],
//   B[k=(lane>>5)*8+j][n=lane&31], C/D col=lane&31,
//   row=(reg&3)+8*(reg>>2)+4*(lane>>5), reg in [0,16).
// Attention R12: KEY-SPLIT waves. Block = 4 waves = 2 heads x 2 key-halves
// (fixed-max softmax partials are additive over keys), two complementary
// passes (qt=63-p, then p) -> 512 blocks x uniform 33-34 iters, 2 blocks/CU
// co-resident the whole kernel (72.5 KB LDS). Per-wave per-iter work is half
// of R10's (8 QK + 8 PV MFMA32), chain halved. Partial (O,lsum) combined
// once per pass via LDS scratch aliasing Kb/Vb.
// ---------------------------------------------------------------------------

typedef __bf16 bf16;
typedef __bf16 bf16x8 __attribute__((ext_vector_type(8)));
typedef __bf16 bf16x4 __attribute__((ext_vector_type(4)));
typedef float f32x4 __attribute__((ext_vector_type(4)));
typedef float f32x16 __attribute__((ext_vector_type(16)));
typedef float float4v __attribute__((ext_vector_type(4)));

#define MFMA_BF16(a, b, c) __builtin_amdgcn_mfma_f32_16x16x32_bf16((a), (b), (c), 0, 0, 0)
#define MFMA32(a, b, c)    __builtin_amdgcn_mfma_f32_32x32x16_bf16((a), (b), (c), 0, 0, 0)

static constexpr int Bz = 2, Lz = 2048, Dz = 1024;
static constexpr int Hz = 16, Gz = 2;
static constexpr int DQKz = 128, DVz = 128;

__device__ __forceinline__ void async_copy16(const bf16* g, bf16* l) {
    __builtin_amdgcn_global_load_lds(
        (const __attribute__((address_space(1))) unsigned int*)g,
        (__attribute__((address_space(3))) unsigned int*)l, 16, 0, 0);
}

// ---------------- prep: cvt q/k/v + all 4 weight transposes, one launch -----
__global__ __launch_bounds__(256) void prep(
    const float* __restrict__ q, const float* __restrict__ k,
    const float* __restrict__ v, bf16* __restrict__ dq,
    bf16* __restrict__ dk, bf16* __restrict__ dv,
    const float* __restrict__ Wq, const float* __restrict__ Wk,
    const float* __restrict__ Wv, const float* __restrict__ Wo,
    bf16* __restrict__ WqT, bf16* __restrict__ WkT,
    bf16* __restrict__ WvT, bf16* __restrict__ WoT)
{
    int bid = blockIdx.x;
    if (bid < 6144) {
        const float* s = bid < 2048 ? q : (bid < 4096 ? k : v);
        bf16* d = bid < 2048 ? dq : (bid < 4096 ? dk : dv);
        int i = (bid & 2047) * 2048 + threadIdx.x * 8;
        float4v a = *(const float4v*)(s + i);
        float4v b = *(const float4v*)(s + i + 4);
        bf16x8 o;
        #pragma unroll
        for (int j = 0; j < 4; ++j) { o[j] = (bf16)a[j]; o[j + 4] = (bf16)b[j]; }
        *(bf16x8*)(d + i) = o;
        return;
    }
    bid -= 6144;
    const float* W; bf16* WT; int K, N;
    if (bid < 2048)      { W = Wq; WT = WqT; K = 1024; N = 2048; }
    else if (bid < 2304) { W = Wk; WT = WkT; K = 1024; N = 256;  bid -= 2048; }
    else if (bid < 2560) { W = Wv; WT = WvT; K = 1024; N = 256;  bid -= 2304; }
    else                 { W = Wo; WT = WoT; K = 2048; N = 1024; bid -= 2560; }
    int tiles_n = N >> 5;
    int n0 = (bid % tiles_n) * 32, k0 = (bid / tiles_n) * 32;

    __shared__ bf16 t[32][33];
    int tx = threadIdx.x & 31, ty = threadIdx.x >> 5;
    #pragma unroll
    for (int i = 0; i < 4; ++i)
        t[ty + i * 8][tx] = (bf16)W[(size_t)(k0 + ty + i * 8) * N + n0 + tx];
    __syncthreads();
    #pragma unroll
    for (int i = 0; i < 4; ++i)
        WT[(size_t)(n0 + ty + i * 8) * K + k0 + tx] = t[tx][ty + i * 8];
}

// ---------------- 4-wave GEMM body: 128x128 tile, 4x4 acc/wave, dbuf --------
template <typename TC>
__device__ __forceinline__ void gemm_tile4(
    const bf16* __restrict__ A, const bf16* __restrict__ BT,
    const float* __restrict__ bias, float scale, TC* __restrict__ C,
    int M, int N, int K, int m0, int n0, bool trans_out,
    bf16 (&As)[2][128 * 64], bf16 (&Bs)[2][128 * 64])
{
    const int tid  = threadIdx.x;        // 256
    const int wave = tid >> 6;
    const int lane = tid & 63;
    const int quad = lane >> 4;
    const int l16  = lane & 15;
    const int sw   = l16 & 7;
    const int wm = wave >> 1, wn = wave & 1;

    f32x4 acc[4][4] = {};

    auto stage = [&](int k0, int buf) {
        #pragma unroll
        for (int s = 0; s < 4; ++s) {
            int i = s * 256 + tid;
            int row = i >> 3, c = (i & 7) ^ (row & 7);
            async_copy16(A + (size_t)(m0 + row) * K + k0 + c * 8, &As[buf][i * 8]);
        }
        #pragma unroll
        for (int s = 0; s < 4; ++s) {
            int i = s * 256 + tid;
            int row = i >> 3, c = (i & 7) ^ (row & 7);
            async_copy16(BT + (size_t)(n0 + row) * K + k0 + c * 8, &Bs[buf][i * 8]);
        }
    };

    stage(0, 0);
    int cur = 0;
    for (int k0 = 0; k0 < K; k0 += 64) {
        __syncthreads();
        if (k0 + 64 < K) stage(k0 + 64, cur ^ 1);

        #pragma unroll
        for (int ks = 0; ks < 2; ++ks) {
            bf16x8 af[4], bfv[4];
            #pragma unroll
            for (int mt = 0; mt < 4; ++mt)
                af[mt] = *(const bf16x8*)(&As[cur][((wm * 64 + mt * 16 + l16) * 8
                                                    + ((ks * 4 + quad) ^ sw)) * 8]);
            #pragma unroll
            for (int nt = 0; nt < 4; ++nt)
                bfv[nt] = *(const bf16x8*)(&Bs[cur][((wn * 64 + nt * 16 + l16) * 8
                                                     + ((ks * 4 + quad) ^ sw)) * 8]);
            #pragma unroll
            for (int mt = 0; mt < 4; ++mt)
                #pragma unroll
                for (int nt = 0; nt < 4; ++nt)
                    acc[mt][nt] = MFMA_BF16(af[mt], bfv[nt], acc[mt][nt]);
        }
        cur ^= 1;
    }

    #pragma unroll
    for (int nt = 0; nt < 4; ++nt) {
        int col = n0 + wn * 64 + nt * 16 + l16;
        float bv = bias[col];
        #pragma unroll
        for (int mt = 0; mt < 4; ++mt) {
            int row = m0 + wm * 64 + mt * 16 + quad * 4;
            if (trans_out) {
                struct V4 { TC v[4]; } o;
                #pragma unroll
                for (int r = 0; r < 4; ++r)
                    o.v[r] = (TC)((acc[mt][nt][r] + bv) * scale);
                *(V4*)(&C[(size_t)col * M + row]) = o;
            } else {
                #pragma unroll
                for (int r = 0; r < 4; ++r)
                    C[(size_t)(row + r) * N + col] =
                        (TC)((acc[mt][nt][r] + bv) * scale);
            }
        }
    }
}

// ---------------- Q+K+V projections: 640 x 256-thr, XCD-swizzled ------------
__global__ __launch_bounds__(256, 2) void proj_qkv(
    const bf16* __restrict__ aq, const bf16* __restrict__ ak,
    const bf16* __restrict__ av, const bf16* __restrict__ WqT,
    const bf16* __restrict__ WkT, const bf16* __restrict__ WvT,
    const float* __restrict__ bq, const float* __restrict__ bk,
    const float* __restrict__ bv, const float* __restrict__ qsc,
    bf16* __restrict__ Qw, bf16* __restrict__ Kw, bf16* __restrict__ VwT)
{
    __shared__ bf16 As[2][128 * 64];
    __shared__ bf16 Bs[2][128 * 64];
    int bid = blockIdx.x;
    if (bid < 512) {
        int xcd = bid & 7, rest = bid >> 3;       // same-m blocks share bid%8
        int n = rest & 15, mg = rest >> 4;
        int m = mg * 8 + xcd;
        float scale = qsc[0] * 0.08838834764831845f * 1.4426950408889634f;
        gemm_tile4<bf16>(aq, WqT, bq, scale, Qw, 4096, 2048, 1024,
                         m * 128, n * 128, false, As, Bs);
    } else if (bid < 576) {
        int b2 = bid - 512;
        gemm_tile4<bf16>(ak, WkT, bk, 1.0f, Kw, 4096, 256, 1024,
                         (b2 >> 1) * 128, (b2 & 1) * 128, false, As, Bs);
    } else {
        int b2 = bid - 576;
        gemm_tile4<bf16>(av, WvT, bv, 1.0f, VwT, 4096, 256, 1024,
                         (b2 >> 1) * 128, (b2 & 1) * 128, true, As, Bs);
    }
}

// ---------------- output projection: 128x64 tiles, 512 blocks, 3/CU ---------
__global__ __launch_bounds__(256, 3) void proj_o(
    const bf16* __restrict__ Cw, const bf16* __restrict__ WoT,
    const float* __restrict__ bo, float* __restrict__ out)
{
    __shared__ bf16 As[2][128 * 64];   // 32 KB
    __shared__ bf16 Bs[2][64 * 64];    // 16 KB -> 48 KB total, 3 blocks/CU

    const int tid  = threadIdx.x;      // 256
    const int wave = tid >> 6;
    const int lane = tid & 63;
    const int quad = lane >> 4;
    const int l16  = lane & 15;
    const int sw   = l16 & 7;
    const int wm = wave >> 1, wn = wave & 1;

    int xcd = blockIdx.x & 7, rest = blockIdx.x >> 3;   // rest 0..63
    int n = rest & 15, mg = rest >> 4;                  // n 0..15, mg 0..3
    int m = mg * 8 + xcd;                               // m 0..31
    const int m0 = m * 128, n0 = n * 64;
    const int M = 4096, N = 1024, K = 2048;

    f32x4 acc[4][2] = {};

    auto stage = [&](int k0, int buf) {
        #pragma unroll
        for (int s = 0; s < 4; ++s) {
            int i = s * 256 + tid;
            int row = i >> 3, c = (i & 7) ^ (row & 7);
            async_copy16(Cw + (size_t)(m0 + row) * K + k0 + c * 8, &As[buf][i * 8]);
        }
        #pragma unroll
        for (int s = 0; s < 2; ++s) {
            int i = s * 256 + tid;
            int row = i >> 3, c = (i & 7) ^ (row & 7);
            async_copy16(WoT + (size_t)(n0 + row) * K + k0 + c * 8, &Bs[buf][i * 8]);
        }
    };

    stage(0, 0);
    int cur = 0;
    for (int k0 = 0; k0 < K; k0 += 64) {
        __syncthreads();
        if (k0 + 64 < K) stage(k0 + 64, cur ^ 1);

        #pragma unroll
        for (int ks = 0; ks < 2; ++ks) {
            bf16x8 af[4], bfv[2];
            #pragma unroll
            for (int mt = 0; mt < 4; ++mt)
                af[mt] = *(const bf16x8*)(&As[cur][((wm * 64 + mt * 16 + l16) * 8
                                                    + ((ks * 4 + quad) ^ sw)) * 8]);
            #pragma unroll
            for (int nt = 0; nt < 2; ++nt)
                bfv[nt] = *(const bf16x8*)(&Bs[cur][((wn * 32 + nt * 16 + l16) * 8
                                                     + ((ks * 4 + quad) ^ sw)) * 8]);
            #pragma unroll
            for (int mt = 0; mt < 4; ++mt)
                #pragma unroll
                for (int nt = 0; nt < 2; ++nt)
                    acc[mt][nt] = MFMA_BF16(af[mt], bfv[nt], acc[mt][nt]);
        }
        cur ^= 1;
    }

    #pragma unroll
    for (int nt = 0; nt < 2; ++nt) {
        int col = n0 + wn * 32 + nt * 16 + l16;
        float bv = bo[col];
        #pragma unroll
        for (int mt = 0; mt < 4; ++mt) {
            int row = m0 + wm * 64 + mt * 16 + quad * 4;
            #pragma unroll
            for (int r = 0; r < 4; ++r)
                out[(size_t)(row + r) * N + col] = acc[mt][nt][r] + bv;
        }
    }
}

// ---------------- flash attention: key-split waves, uniform two-pass --------
// grid 512 x 256 thr. Decode: b=bid&1, g=(bid>>1)&1, hp=(bid>>2)&3, p=bid>>4.
// wave w: head = g*8 + hp*2 + (w&1); kg = w>>1 (key half of each 64-key tile).
// Pass 0: qt = 63-p; pass 1: qt = p (32-row q-tiles) -> uniform 33-34 iters.
// Partial (O,lsum) over key halves combined per pass via LDS scratch.
__global__ __launch_bounds__(256, 2) void attn_fused(
    const bf16* __restrict__ Q,    // [B*L, H*128], pre-scaled
    const bf16* __restrict__ Kp,   // [B*L, G*128]
    const bf16* __restrict__ VT,   // [G*128, B*L]
    bf16* __restrict__ ctx)        // [B*L, H*128]
{
    __shared__ bf16 Kb[2][64 * 128];   // 32 KB  [key][dqk] swz; scratch wave2
    __shared__ bf16 Vb[2][128 * 64];   // 32 KB  [dv][key] swz; scratch wave3
    __shared__ bf16 Ps[4][32 * 32];    // 8 KB   per-wave P^T [qrow][key32]
    __shared__ float Ls[4 * 32];       // per-wave per-qrow partial sums

    const int tid  = threadIdx.x;
    const int wave = tid >> 6;
    const int lane = tid & 63;
    const int l32  = lane & 31;
    const int half = lane >> 5;
    const int sw8  = lane & 7;

    const int bid = blockIdx.x;
    const int b   = bid & 1;
    const int g   = (bid >> 1) & 1;
    const int hp  = (bid >> 2) & 3;
    const int p   = bid >> 4;          // 0..31
    const int h   = g * 8 + hp * 2 + (wave & 1);
    const int kg  = wave >> 1;         // key half: 0 -> keys 0..31, 1 -> 32..63

    const bf16* kgbase = Kp + (size_t)(b * Lz) * (Gz * DQKz) + g * DQKz;
    const bf16* vgbase = VT + (size_t)(g * DVz) * (Bz * Lz) + b * Lz;

    auto stage = [&](int kt, int buf) {
        const bf16* kb = kgbase + (size_t)(kt * 64) * (Gz * DQKz);
        #pragma unroll
        for (int s = 0; s < 4; ++s) {
            int i = s * 256 + tid;
            int key = i >> 4, c = (i & 15) ^ (key & 7);
            async_copy16(kb + (size_t)key * (Gz * DQKz) + c * 8, &Kb[buf][i * 8]);
        }
        const bf16* vb = vgbase + kt * 64;
        #pragma unroll
        for (int s = 0; s < 4; ++s) {
            int i = s * 256 + tid;
            int dv = i >> 3, c = (i & 7) ^ (dv & 7);
            async_copy16(vb + (size_t)dv * (Bz * Lz) + c * 8, &Vb[buf][i * 8]);
        }
    };

    bf16* ps = Ps[wave];

    for (int pass = 0; pass < 2; ++pass) {
        const int qt   = pass == 0 ? (63 - p) : p;
        const int q0   = qt * 32;
        const int nkt  = (qt >> 1) + 1;
        const int qrow = q0 + l32;

        // Q B-frags: B[k=(lane>>5)*8+j][n=qrow=lane&31]
        bf16x8 qf[8];
        {
            const bf16* qbase = Q + (size_t)(b * Lz + qrow) * (Hz * DQKz) + h * DQKz;
            #pragma unroll
            for (int kc = 0; kc < 8; ++kc)
                qf[kc] = *(const bf16x8*)(qbase + kc * 16 + half * 8);
        }

        f32x16 oacc[4] = {};       // O^T[dv][q]: dv = dvg*32 + rowmap, q = l32
        float lsum = 0.0f;

        if (pass) __syncthreads();  // scratch/buffers still in use from pass 0
        stage(0, 0);
        int cur = 0;

        for (int kt = 0; kt < nkt; ++kt) {
            __syncthreads();            // drains async loads issued last iter
            if (kt + 1 < nkt) stage(kt + 1, cur ^ 1);

            const bf16* kcur = Kb[cur];
            const bf16* vcur = Vb[cur];

            // S^T = K Q^T over this wave's 32 keys (kg half): 8 k-chunks
            f32x16 sacc = {};
            {
                const int row = kg * 32 + l32;
                #pragma unroll
                for (int kc = 0; kc < 8; ++kc) {
                    bf16x8 kf = *(const bf16x8*)(&kcur[row * 128
                                                       + (((kc * 2 + half) ^ sw8) * 8)]);
                    sacc = MFMA32(kf, qf[kc], sacc);
                }
            }

            // P = exp2(S) (unshifted), mask only diagonal tile
            const int kv0 = kt * 64;
            float pv[16];
            if (kt == nkt - 1) {
                #pragma unroll
                for (int r = 0; r < 16; ++r) {
                    int key = kv0 + kg * 32 + (r & 3) + 8 * (r >> 2) + 4 * half;
                    pv[r] = (key > qrow) ? 0.0f : exp2f(sacc[r]);
                }
            } else {
                #pragma unroll
                for (int r = 0; r < 16; ++r)
                    pv[r] = exp2f(sacc[r]);
            }
            #pragma unroll
            for (int r = 0; r < 16; ++r) lsum += pv[r];

            // P^T -> per-wave LDS [qrow=l32][key local 0..31] (stride 16 words
            // between lanes -> 2-way, free)
            #pragma unroll
            for (int i = 0; i < 4; ++i) {
                bf16x4 pk;
                #pragma unroll
                for (int r = 0; r < 4; ++r) pk[r] = (bf16)pv[i * 4 + r];
                *(bf16x4*)(&ps[l32 * 32 + 8 * i + 4 * half]) = pk;
            }

            // O^T += V^T P^T over this wave's 32 keys: 2 k-chunks x 4 dv-groups
            #pragma unroll
            for (int kc = 0; kc < 2; ++kc) {
                bf16x8 pf = *(const bf16x8*)(&ps[l32 * 32 + kc * 16 + half * 8]);
                #pragma unroll
                for (int dvg = 0; dvg < 4; ++dvg) {
                    const int row = dvg * 32 + l32;
                    int chunk = kg * 4 + kc * 2 + half;
                    bf16x8 vf = *(const bf16x8*)(&vcur[row * 64
                                                       + ((chunk ^ sw8) * 8)]);
                    oacc[dvg] = MFMA32(vf, pf, oacc[dvg]);
                }
            }
            cur ^= 1;
        }

        // lsum: within-wave, other half-wave holds the other 16 of 32 keys
        lsum += __shfl_xor(lsum, 32);

        // combine key halves: waves 2,3 (kg=1) dump partials, waves 0,1 add
        __syncthreads();
        if (kg == 1) {
            float* sc = (wave == 2) ? (float*)&Kb[0][0] : (float*)&Vb[0][0];
            #pragma unroll
            for (int dvg = 0; dvg < 4; ++dvg) {
                #pragma unroll
                for (int i = 0; i < 4; ++i) {
                    float4v o4;
                    #pragma unroll
                    for (int r = 0; r < 4; ++r) o4[r] = oacc[dvg][i * 4 + r];
                    *(float4v*)(&sc[lane * 68 + dvg * 16 + i * 4]) = o4;
                }
            }
            if (half == 0) Ls[wave * 32 + l32] = lsum;
        }
        __syncthreads();
        if (kg == 0) {
            float* sc = (wave == 0) ? (float*)&Kb[0][0] : (float*)&Vb[0][0];
            #pragma unroll
            for (int dvg = 0; dvg < 4; ++dvg) {
                #pragma unroll
                for (int i = 0; i < 4; ++i) {
                    float4v o4 = *(const float4v*)(&sc[lane * 68 + dvg * 16 + i * 4]);
                    #pragma unroll
                    for (int r = 0; r < 4; ++r) oacc[dvg][i * 4 + r] += o4[r];
                }
            }
            const float inv = 1.0f / (lsum + Ls[(wave + 2) * 32 + l32]);

            // epilogue: dv = dvg*32 + 8*i + 4*half + (r&3), q = qrow
            bf16* cb = ctx + (size_t)(b * Lz + qrow) * (Hz * DVz) + h * DVz;
            #pragma unroll
            for (int dvg = 0; dvg < 4; ++dvg) {
                #pragma unroll
                for (int i = 0; i < 4; ++i) {
                    bf16x4 o4;
                    #pragma unroll
                    for (int r = 0; r < 4; ++r)
                        o4[r] = (bf16)(oacc[dvg][i * 4 + r] * inv);
                    *(bf16x4*)(&cb[dvg * 32 + 8 * i + 4 * half]) = o4;
                }
            }
        }
        // pass-top __syncthreads() protects scratch before restaging
    }
}

// ---------------------------------------------------------------------------
extern "C" void kernel_launch(void* const* d_in, const int* in_sizes, int n_in,
                              void* d_out, int out_size, void* d_ws, size_t ws_size,
                              hipStream_t stream)
{
    (void)in_sizes; (void)n_in; (void)out_size; (void)ws_size;

    const float* in_q = (const float*)d_in[0];
    const float* in_k = (const float*)d_in[1];
    const float* in_v = (const float*)d_in[2];
    const float* Wq   = (const float*)d_in[3];
    const float* bq   = (const float*)d_in[4];
    const float* Wk   = (const float*)d_in[5];
    const float* bk   = (const float*)d_in[6];
    const float* Wv   = (const float*)d_in[7];
    const float* bv   = (const float*)d_in[8];
    const float* Wo   = (const float*)d_in[9];
    const float* bo   = (const float*)d_in[10];
    const float* qsc  = (const float*)d_in[11];
    float* out = (float*)d_out;

    const int M = Bz * Lz;                       // 4096

    // workspace (bf16 elems), ~53 MB; ak/av alias Cw (consumed before attn
    // writes ctx there).
    bf16* aq  = (bf16*)d_ws;                     // 4M
    bf16* WqT = aq  + (size_t)M * Dz;            // 2M
    bf16* WkT = WqT + (size_t)2048 * 1024;       // 0.25M
    bf16* WvT = WkT + (size_t)256 * 1024;        // 0.25M
    bf16* WoT = WvT + (size_t)256 * 1024;        // 2M
    bf16* Qw  = WoT + (size_t)1024 * 2048;       // 8M
    bf16* Kw  = Qw  + (size_t)M * 2048;          // 1M
    bf16* VwT = Kw  + (size_t)M * 256;           // 1M
    bf16* Cw  = VwT + (size_t)256 * M;           // 8M
    bf16* ak  = Cw;                              // alias (4M)
    bf16* av  = Cw + (size_t)M * Dz;             // alias (4M)

    // 1) prep: cvt + weight transposes
    prep<<<dim3(10752), dim3(256), 0, stream>>>(
        in_q, in_k, in_v, aq, ak, av, Wq, Wk, Wv, Wo, WqT, WkT, WvT, WoT);

    // 2) Q/K/V projections (640 x 256-thr, 4x4 acc, XCD-swizzled)
    proj_qkv<<<dim3(640), dim3(256), 0, stream>>>(
        aq, ak, av, WqT, WkT, WvT, bq, bk, bv, qsc, Qw, Kw, VwT);

    // 3) attention: key-split waves, uniform two-pass, 512 blocks 2/CU
    attn_fused<<<dim3(512), dim3(256), 0, stream>>>(Qw, Kw, VwT, Cw);

    // 4) output projection -> fp32 out (128x64 tiles, 3 blocks/CU)
    proj_o<<<dim3(512), dim3(256), 0, stream>>>(Cw, WoT, bo, out);
}